// Round 2
// baseline (1130.779 us; speedup 1.0000x reference)
//
#include <hip/hip_runtime.h>
#include <hip/hip_bf16.h>

#define N_NODES 100000
#define N_EDGES 3200000
#define IN_DIM 128
#define HIDDEN 64
#define N_GRAPHS 512
#define SCAN_BLOCKS 391   // ceil(N_NODES/256)

typedef __hip_bfloat16 bf16;
__device__ __forceinline__ float b2f(bf16 v) { return __bfloat162float(v); }

// ---------------- CSR build ----------------
__global__ void deg_count_kernel(const int* __restrict__ dst, int* __restrict__ deg) {
    int e = blockIdx.x * blockDim.x + threadIdx.x;
    if (e < N_EDGES) atomicAdd(&deg[dst[e]], 1);
}

__global__ __launch_bounds__(256) void scan1_kernel(const int* __restrict__ cnt,
                                                    int* __restrict__ partials) {
    __shared__ int sd[256];
    int t = threadIdx.x;
    int i = blockIdx.x * 256 + t;
    sd[t] = (i < N_NODES) ? cnt[i] : 0;
    __syncthreads();
    for (int s = 128; s > 0; s >>= 1) {
        if (t < s) sd[t] += sd[t + s];
        __syncthreads();
    }
    if (t == 0) partials[blockIdx.x] = sd[0];
}

__global__ __launch_bounds__(512) void scan2_kernel(int* __restrict__ partials) {
    __shared__ int sd[512];
    int t = threadIdx.x;
    int v = (t < SCAN_BLOCKS) ? partials[t] : 0;
    sd[t] = v;
    __syncthreads();
    for (int off = 1; off < 512; off <<= 1) {
        int u = (t >= off) ? sd[t - off] : 0;
        __syncthreads();
        sd[t] += u;
        __syncthreads();
    }
    partials[t] = sd[t] - v;   // exclusive prefix
}

__global__ __launch_bounds__(256) void scan3_kernel(const int* __restrict__ cnt,
                                                    const int* __restrict__ partials,
                                                    int* __restrict__ base,
                                                    float* __restrict__ dis) {
    __shared__ int sd[256];
    int t = threadIdx.x;
    int i = blockIdx.x * 256 + t;
    int v = (i < N_NODES) ? cnt[i] : 0;
    sd[t] = v;
    __syncthreads();
    for (int off = 1; off < 256; off <<= 1) {
        int u = (t >= off) ? sd[t - off] : 0;
        __syncthreads();
        sd[t] += u;
        __syncthreads();
    }
    if (i < N_NODES) {
        base[i] = partials[blockIdx.x] + sd[t] - v;     // exclusive
        dis[i] = rsqrtf((float)(v + 1));                // +1 self-loop
    }
    if (blockIdx.x == 0 && t == 0) base[N_NODES] = N_EDGES;
}

__global__ void fill_kernel(const int* __restrict__ src, const int* __restrict__ dst,
                            const int* __restrict__ base, int* __restrict__ fcnt,
                            int* __restrict__ csr) {
    int e = blockIdx.x * blockDim.x + threadIdx.x;
    if (e < N_EDGES) {
        int d = dst[e];
        int pos = base[d] + atomicAdd(&fcnt[d], 1);
        csr[pos] = src[e];
    }
}

// ---------------- GEMM: hd chunk-major = bf16((in[node] @ W) * dis[node]) ---
// hd layout: [4 chunks][N_NODES][16] bf16 — chunk c holds features [16c,16c+16).
// Lane-resident W column + wave-uniform x-row via scalar cache; pure v_fmac.
template <int K>
__global__ __launch_bounds__(256) void gemm_kernel(
        const float* __restrict__ in, const float* __restrict__ W,
        const float* __restrict__ dis, bf16* __restrict__ hd) {
    int tid = threadIdx.x;
    int lane = tid & 63;
    float Wr[K];
    #pragma unroll
    for (int k = 0; k < K; ++k) Wr[k] = W[k * HIDDEN + lane];   // coalesced
    int w = __builtin_amdgcn_readfirstlane(tid >> 6);           // provably uniform
    int wave = blockIdx.x * 4 + w;
    int nw = gridDim.x * 4;
    // chunk-major store base for this lane's feature
    bf16* ob = hd + (size_t)(lane >> 4) * ((size_t)N_NODES * 16) + (lane & 15);
    for (int n0 = wave * 4; n0 < N_NODES; n0 += nw * 4) {
        const float* xr = in + (size_t)n0 * K;
        float a0 = 0.f, a1 = 0.f, a2 = 0.f, a3 = 0.f;
        #pragma unroll
        for (int k = 0; k < K; ++k) {
            float wv = Wr[k];
            a0 = fmaf(xr[k],         wv, a0);
            a1 = fmaf(xr[K + k],     wv, a1);
            a2 = fmaf(xr[2 * K + k], wv, a2);
            a3 = fmaf(xr[3 * K + k], wv, a3);
        }
        ob[(size_t)(n0 + 0) * 16] = __float2bfloat16(a0 * dis[n0]);
        ob[(size_t)(n0 + 1) * 16] = __float2bfloat16(a1 * dis[n0 + 1]);
        ob[(size_t)(n0 + 2) * 16] = __float2bfloat16(a2 * dis[n0 + 2]);
        ob[(size_t)(n0 + 3) * 16] = __float2bfloat16(a3 * dis[n0 + 3]);
    }
}

// ---------------- pull (per feature-chunk): one wave per node --------------
// Chunk working set = 3.2 MB < 4 MiB per-XCD L2 -> gathers are L2 hits.
// 4 edges per load instr: 16 lanes/edge, lane reads 2B of the 32B segment.
// slot = lane>>4 picks the edge within the group; feat = lane&15.
// csr read is streaming-once -> nontemporal to protect chunk residency.
template <int POOL>
__global__ __launch_bounds__(256) void pull_kernel(
        const bf16* __restrict__ hdc,   // chunk base: [N_NODES][16] bf16
        const float* __restrict__ dis,
        const int* __restrict__ base, const int* __restrict__ csr,
        const float* __restrict__ bias,   // pre-offset by chunk*16
        float* __restrict__ act,          // [N][64] f32
        const int* __restrict__ batch, float* __restrict__ pool,
        float* __restrict__ cnt, int coff /* chunk*16 */) {
    int w = threadIdx.x >> 6, lane = threadIdx.x & 63;
    int node = blockIdx.x * 4 + w;
    if (node >= N_NODES) return;   // whole-wave uniform exit
    int feat = lane & 15;
    int slot = lane >> 4;
    int beg = base[node], end = base[node + 1];
    float a = 0.f;
    for (int j = beg; j < end; j += 64) {
        int rem = end - j;
        int m = rem < 64 ? rem : 64;
        int idx = (lane < m) ? __builtin_nontemporal_load(&csr[j + lane]) : 0;
        int t = 0;
        for (; t + 32 <= m; t += 32) {   // 8 loads (32 edges) in flight
            int s0 = __shfl(idx, t + slot);
            int s1 = __shfl(idx, t + 4 + slot);
            int s2 = __shfl(idx, t + 8 + slot);
            int s3 = __shfl(idx, t + 12 + slot);
            int s4 = __shfl(idx, t + 16 + slot);
            int s5 = __shfl(idx, t + 20 + slot);
            int s6 = __shfl(idx, t + 24 + slot);
            int s7 = __shfl(idx, t + 28 + slot);
            float v0 = b2f(hdc[(size_t)s0 * 16 + feat]);
            float v1 = b2f(hdc[(size_t)s1 * 16 + feat]);
            float v2 = b2f(hdc[(size_t)s2 * 16 + feat]);
            float v3 = b2f(hdc[(size_t)s3 * 16 + feat]);
            float v4 = b2f(hdc[(size_t)s4 * 16 + feat]);
            float v5 = b2f(hdc[(size_t)s5 * 16 + feat]);
            float v6 = b2f(hdc[(size_t)s6 * 16 + feat]);
            float v7 = b2f(hdc[(size_t)s7 * 16 + feat]);
            a += ((v0 + v1) + (v2 + v3)) + ((v4 + v5) + (v6 + v7));
        }
        if (t < m) {
            // remainder < 32 edges: predicated 8-group block.
            // e <= t+31 <= 63 (t in {0,32}), so shfl src lane is valid.
            #pragma unroll
            for (int u = 0; u < 8; ++u) {
                int e = t + u * 4 + slot;
                int s = __shfl(idx, e);
                if (e < m) a += b2f(hdc[(size_t)s * 16 + feat]);
            }
        }
    }
    // sum the 4 edge-slot partials for this feature
    a += __shfl_xor(a, 16);
    a += __shfl_xor(a, 32);
    float self = b2f(hdc[(size_t)node * 16 + feat]);
    float row = dis[node] * (a + self) + bias[feat];
    float v = row > 0.f ? row : 0.f;
    if (POOL == 0) {
        if (slot == 0)
            __builtin_nontemporal_store(v, &act[(size_t)node * HIDDEN + coff + feat]);
    } else {
        if (slot == 0) {
            int g = batch[node];
            atomicAdd(&pool[g * HIDDEN + coff + feat], v);
            if (feat == 0 && coff == 0) atomicAdd(&cnt[g], 1.0f);
        }
    }
}

__global__ void final_kernel(const float* __restrict__ pool,
                             const float* __restrict__ cnt,
                             float* __restrict__ out) {
    int i = blockIdx.x * blockDim.x + threadIdx.x;
    if (i < N_GRAPHS * HIDDEN) {
        float c = cnt[i >> 6];
        c = c > 1.0f ? c : 1.0f;
        out[i] = pool[i] / c;
    }
}

extern "C" void kernel_launch(void* const* d_in, const int* in_sizes, int n_in,
                              void* d_out, int out_size, void* d_ws, size_t ws_size,
                              hipStream_t stream) {
    const float* x  = (const float*)d_in[0];
    const float* W1 = (const float*)d_in[1];
    const float* b1 = (const float*)d_in[2];
    const float* W2 = (const float*)d_in[3];
    const float* b2 = (const float*)d_in[4];
    const int* edge_index = (const int*)d_in[5];
    const int* batch      = (const int*)d_in[6];
    float* out = (float*)d_out;
    (void)in_sizes; (void)n_in; (void)out_size; (void)ws_size;

    char* ws = (char*)d_ws;
    int*   deg_cnt  = (int*)  (ws + 0);         // 400000
    int*   fcnt     = (int*)  (ws + 400000);    // 400000
    float* pool     = (float*)(ws + 800000);    // 131072
    float* cnt      = (float*)(ws + 931072);    // 2048
    int*   partials = (int*)  (ws + 933120);    // 2048
    float* dis      = (float*)(ws + 935168);    // 400000
    int*   base     = (int*)  (ws + 1335168);   // 400032 (padded)
    int*   csr      = (int*)  (ws + 1735200);   // 12800000
    bf16*  hd       = (bf16*) (ws + 14535200);  // 12800000 (4 chunks x N x 16)
    float* act      = (float*)(ws + 27335200);  // 25600000 -> ends 52935200

    const int* srcv = edge_index;            // edge_index[0]
    const int* dstv = edge_index + N_EDGES;  // edge_index[1]

    const size_t CHUNK = (size_t)N_NODES * 16;   // bf16 elems per chunk
    const int PBLK = (N_NODES + 3) / 4;

    // zero: deg_cnt, fcnt, pool, cnt (contiguous region)
    hipMemsetAsync(ws, 0, 933120, stream);

    // CSR build (reused by both layers)
    deg_count_kernel<<<(N_EDGES + 255) / 256, 256, 0, stream>>>(dstv, deg_cnt);
    scan1_kernel<<<SCAN_BLOCKS, 256, 0, stream>>>(deg_cnt, partials);
    scan2_kernel<<<1, 512, 0, stream>>>(partials);
    scan3_kernel<<<SCAN_BLOCKS, 256, 0, stream>>>(deg_cnt, partials, base, dis);
    fill_kernel<<<(N_EDGES + 255) / 256, 256, 0, stream>>>(srcv, dstv, base, fcnt, csr);

    // layer 1: hd = bf16((x@W1)*dis) ; act = relu(dis*(gather+self) + b1)
    gemm_kernel<IN_DIM><<<1024, 256, 0, stream>>>(x, W1, dis, hd);
    for (int c = 0; c < 4; ++c)
        pull_kernel<0><<<PBLK, 256, 0, stream>>>(hd + c * CHUNK, dis, base, csr,
                                                 b1 + c * 16, act,
                                                 nullptr, nullptr, nullptr, c * 16);

    // layer 2: hd = bf16((act@W2)*dis) ; fused relu+b2+mean-pool atomics
    gemm_kernel<HIDDEN><<<1024, 256, 0, stream>>>(act, W2, dis, hd);
    for (int c = 0; c < 4; ++c)
        pull_kernel<1><<<PBLK, 256, 0, stream>>>(hd + c * CHUNK, dis, base, csr,
                                                 b2 + c * 16, nullptr,
                                                 batch, pool, cnt, c * 16);

    final_kernel<<<(N_GRAPHS * HIDDEN + 255) / 256, 256, 0, stream>>>(pool, cnt, out);
}

// Round 3
// 1008.064 us; speedup vs baseline: 1.1217x; 1.1217x over previous
//
#include <hip/hip_runtime.h>
#include <hip/hip_bf16.h>

#define N_NODES 100000
#define N_EDGES 3200000
#define IN_DIM 128
#define HIDDEN 64
#define N_GRAPHS 512
#define SCAN_BLOCKS 391   // ceil(N_NODES/256)

typedef __hip_bfloat16 bf16;
__device__ __forceinline__ float b2f(bf16 v) { return __bfloat162float(v); }

// accumulate 8 bf16 features packed in an int4 into f32 accumulators
__device__ __forceinline__ void acc8(float* a, int4 p) {
    unsigned x = (unsigned)p.x, y = (unsigned)p.y, z = (unsigned)p.z, w = (unsigned)p.w;
    a[0] += __uint_as_float(x << 16);
    a[1] += __uint_as_float(x & 0xFFFF0000u);
    a[2] += __uint_as_float(y << 16);
    a[3] += __uint_as_float(y & 0xFFFF0000u);
    a[4] += __uint_as_float(z << 16);
    a[5] += __uint_as_float(z & 0xFFFF0000u);
    a[6] += __uint_as_float(w << 16);
    a[7] += __uint_as_float(w & 0xFFFF0000u);
}

// ---------------- CSR build ----------------
__global__ void deg_count_kernel(const int* __restrict__ dst, int* __restrict__ deg) {
    int e = blockIdx.x * blockDim.x + threadIdx.x;
    if (e < N_EDGES) atomicAdd(&deg[dst[e]], 1);
}

__global__ __launch_bounds__(256) void scan1_kernel(const int* __restrict__ cnt,
                                                    int* __restrict__ partials) {
    __shared__ int sd[256];
    int t = threadIdx.x;
    int i = blockIdx.x * 256 + t;
    sd[t] = (i < N_NODES) ? cnt[i] : 0;
    __syncthreads();
    for (int s = 128; s > 0; s >>= 1) {
        if (t < s) sd[t] += sd[t + s];
        __syncthreads();
    }
    if (t == 0) partials[blockIdx.x] = sd[0];
}

__global__ __launch_bounds__(512) void scan2_kernel(int* __restrict__ partials) {
    __shared__ int sd[512];
    int t = threadIdx.x;
    int v = (t < SCAN_BLOCKS) ? partials[t] : 0;
    sd[t] = v;
    __syncthreads();
    for (int off = 1; off < 512; off <<= 1) {
        int u = (t >= off) ? sd[t - off] : 0;
        __syncthreads();
        sd[t] += u;
        __syncthreads();
    }
    partials[t] = sd[t] - v;   // exclusive prefix
}

__global__ __launch_bounds__(256) void scan3_kernel(const int* __restrict__ cnt,
                                                    const int* __restrict__ partials,
                                                    int* __restrict__ base,
                                                    float* __restrict__ dis) {
    __shared__ int sd[256];
    int t = threadIdx.x;
    int i = blockIdx.x * 256 + t;
    int v = (i < N_NODES) ? cnt[i] : 0;
    sd[t] = v;
    __syncthreads();
    for (int off = 1; off < 256; off <<= 1) {
        int u = (t >= off) ? sd[t - off] : 0;
        __syncthreads();
        sd[t] += u;
        __syncthreads();
    }
    if (i < N_NODES) {
        base[i] = partials[blockIdx.x] + sd[t] - v;     // exclusive
        dis[i] = rsqrtf((float)(v + 1));                // +1 self-loop
    }
    if (blockIdx.x == 0 && t == 0) base[N_NODES] = N_EDGES;
}

__global__ void fill_kernel(const int* __restrict__ src, const int* __restrict__ dst,
                            const int* __restrict__ base, int* __restrict__ fcnt,
                            int* __restrict__ csr) {
    int e = blockIdx.x * blockDim.x + threadIdx.x;
    if (e < N_EDGES) {
        int d = dst[e];
        int pos = base[d] + atomicAdd(&fcnt[d], 1);
        csr[pos] = src[e];
    }
}

// ---------------- GEMM: hd[node] = bf16((in[node] @ W) * dis[node]) ----------
// Row-major hd [N][64]. Lane-resident W column + wave-uniform x-row.
template <int K>
__global__ __launch_bounds__(256) void gemm_kernel(
        const float* __restrict__ in, const float* __restrict__ W,
        const float* __restrict__ dis, bf16* __restrict__ hd) {
    int tid = threadIdx.x;
    int lane = tid & 63;
    float Wr[K];
    #pragma unroll
    for (int k = 0; k < K; ++k) Wr[k] = W[k * HIDDEN + lane];   // coalesced
    int w = __builtin_amdgcn_readfirstlane(tid >> 6);           // provably uniform
    int wave = blockIdx.x * 4 + w;
    int nw = gridDim.x * 4;
    for (int n0 = wave * 4; n0 < N_NODES; n0 += nw * 4) {
        const float* xr = in + (size_t)n0 * K;
        float a0 = 0.f, a1 = 0.f, a2 = 0.f, a3 = 0.f;
        #pragma unroll
        for (int k = 0; k < K; ++k) {
            float wv = Wr[k];
            a0 = fmaf(xr[k],         wv, a0);
            a1 = fmaf(xr[K + k],     wv, a1);
            a2 = fmaf(xr[2 * K + k], wv, a2);
            a3 = fmaf(xr[3 * K + k], wv, a3);
        }
        bf16* o = hd + (size_t)n0 * HIDDEN + lane;
        o[0]          = __float2bfloat16(a0 * dis[n0]);
        o[HIDDEN]     = __float2bfloat16(a1 * dis[n0 + 1]);
        o[2 * HIDDEN] = __float2bfloat16(a2 * dis[n0 + 2]);
        o[3 * HIDDEN] = __float2bfloat16(a3 * dis[n0 + 3]);
    }
}

// ---------------- pull: row = dis[d]*(sum_src hd[src] + hd[d]) + bias --------
// Wide gather: 8 lanes per edge (16B int4 = 8 bf16 feats/lane), 8 edges per
// load instruction -> scattered-VMEM instr count drops 8x vs 1-edge/instr.
// slot = lane>>3 picks the edge; sub = lane&7 picks the 16B feature block.
template <int POOL>
__global__ __launch_bounds__(256) void pull_kernel(
        const bf16* __restrict__ hd, const float* __restrict__ dis,
        const int* __restrict__ base, const int* __restrict__ csr,
        const float* __restrict__ bias,
        float* __restrict__ act,
        const int* __restrict__ batch, float* __restrict__ pool,
        float* __restrict__ cnt) {
    int w = threadIdx.x >> 6, lane = threadIdx.x & 63;
    int node = blockIdx.x * 4 + w;
    if (node >= N_NODES) return;   // whole-wave uniform exit
    int slot = lane >> 3;          // edge slot 0..7
    int sub  = lane & 7;           // 16B feature block 0..7
    const int4* hp = (const int4*)hd;   // 8 int4 per 64-feat row
    float a[8] = {0.f, 0.f, 0.f, 0.f, 0.f, 0.f, 0.f, 0.f};
    int beg = base[node], end = base[node + 1];
    for (int j = beg; j < end; j += 64) {
        int rem = end - j;
        int m = rem < 64 ? rem : 64;
        int idx = (lane < m) ? csr[j + lane] : 0;
        int t = 0;
        for (; t + 32 <= m; t += 32) {   // 4 wide loads = 32 edges in flight
            int s0 = __shfl(idx, t + slot);
            int s1 = __shfl(idx, t + 8 + slot);
            int s2 = __shfl(idx, t + 16 + slot);
            int s3 = __shfl(idx, t + 24 + slot);
            int4 p0 = hp[(size_t)s0 * 8 + sub];
            int4 p1 = hp[(size_t)s1 * 8 + sub];
            int4 p2 = hp[(size_t)s2 * 8 + sub];
            int4 p3 = hp[(size_t)s3 * 8 + sub];
            acc8(a, p0);
            acc8(a, p1);
            acc8(a, p2);
            acc8(a, p3);
        }
        if (t < m) {
            #pragma unroll
            for (int g = 0; g < 4; ++g) {
                if (t + g * 8 < m) {            // wave-uniform group guard
                    int e = t + g * 8 + slot;   // <= 63, valid shfl lane
                    int s = __shfl(idx, e);     // e>=m lanes read idx=0 (safe)
                    int4 p = hp[(size_t)s * 8 + sub];
                    if (e < m) acc8(a, p);      // per-lane mask
                }
            }
        }
    }
    // reduce over the 8 edge slots (lane bits 3,4,5)
    #pragma unroll
    for (int d = 8; d <= 32; d <<= 1) {
        #pragma unroll
        for (int k = 0; k < 8; ++k) a[k] += __shfl_xor(a[k], d);
    }
    // self row + bias + relu
    int4 ps = hp[(size_t)node * 8 + sub];
    float s8[8] = {0.f, 0.f, 0.f, 0.f, 0.f, 0.f, 0.f, 0.f};
    acc8(s8, ps);
    float dn = dis[node];
    const float4* bp = (const float4*)bias;
    float4 b0 = bp[sub * 2], b1 = bp[sub * 2 + 1];
    float r[8];
    r[0] = dn * (a[0] + s8[0]) + b0.x;
    r[1] = dn * (a[1] + s8[1]) + b0.y;
    r[2] = dn * (a[2] + s8[2]) + b0.z;
    r[3] = dn * (a[3] + s8[3]) + b0.w;
    r[4] = dn * (a[4] + s8[4]) + b1.x;
    r[5] = dn * (a[5] + s8[5]) + b1.y;
    r[6] = dn * (a[6] + s8[6]) + b1.z;
    r[7] = dn * (a[7] + s8[7]) + b1.w;
    #pragma unroll
    for (int k = 0; k < 8; ++k) r[k] = r[k] > 0.f ? r[k] : 0.f;
    if (POOL == 0) {
        if (slot == 0) {
            float4* op = (float4*)(act + (size_t)node * HIDDEN + sub * 8);
            op[0] = make_float4(r[0], r[1], r[2], r[3]);
            op[1] = make_float4(r[4], r[5], r[6], r[7]);
        }
    } else {
        if (slot == 0) {
            int g = batch[node];
            float* pb = pool + g * HIDDEN + sub * 8;
            #pragma unroll
            for (int k = 0; k < 8; ++k) atomicAdd(pb + k, r[k]);
            if (lane == 0) atomicAdd(&cnt[g], 1.0f);
        }
    }
}

__global__ void final_kernel(const float* __restrict__ pool,
                             const float* __restrict__ cnt,
                             float* __restrict__ out) {
    int i = blockIdx.x * blockDim.x + threadIdx.x;
    if (i < N_GRAPHS * HIDDEN) {
        float c = cnt[i >> 6];
        c = c > 1.0f ? c : 1.0f;
        out[i] = pool[i] / c;
    }
}

extern "C" void kernel_launch(void* const* d_in, const int* in_sizes, int n_in,
                              void* d_out, int out_size, void* d_ws, size_t ws_size,
                              hipStream_t stream) {
    const float* x  = (const float*)d_in[0];
    const float* W1 = (const float*)d_in[1];
    const float* b1 = (const float*)d_in[2];
    const float* W2 = (const float*)d_in[3];
    const float* b2 = (const float*)d_in[4];
    const int* edge_index = (const int*)d_in[5];
    const int* batch      = (const int*)d_in[6];
    float* out = (float*)d_out;
    (void)in_sizes; (void)n_in; (void)out_size; (void)ws_size;

    char* ws = (char*)d_ws;
    int*   deg_cnt  = (int*)  (ws + 0);         // 400000
    int*   fcnt     = (int*)  (ws + 400000);    // 400000
    float* pool     = (float*)(ws + 800000);    // 131072
    float* cnt      = (float*)(ws + 931072);    // 2048
    int*   partials = (int*)  (ws + 933120);    // 2048
    float* dis      = (float*)(ws + 935168);    // 400000
    int*   base     = (int*)  (ws + 1335168);   // 400032 (padded)
    int*   csr      = (int*)  (ws + 1735200);   // 12800000
    bf16*  hd       = (bf16*) (ws + 14535200);  // 12800000
    float* act      = (float*)(ws + 27335200);  // 25600000 -> ends 52935200

    const int* srcv = edge_index;            // edge_index[0]
    const int* dstv = edge_index + N_EDGES;  // edge_index[1]

    const int PBLK = (N_NODES + 3) / 4;

    // zero: deg_cnt, fcnt, pool, cnt (contiguous region)
    hipMemsetAsync(ws, 0, 933120, stream);

    // CSR build (reused by both layers)
    deg_count_kernel<<<(N_EDGES + 255) / 256, 256, 0, stream>>>(dstv, deg_cnt);
    scan1_kernel<<<SCAN_BLOCKS, 256, 0, stream>>>(deg_cnt, partials);
    scan2_kernel<<<1, 512, 0, stream>>>(partials);
    scan3_kernel<<<SCAN_BLOCKS, 256, 0, stream>>>(deg_cnt, partials, base, dis);
    fill_kernel<<<(N_EDGES + 255) / 256, 256, 0, stream>>>(srcv, dstv, base, fcnt, csr);

    // layer 1: hd = bf16((x@W1)*dis) ; act = relu(dis*(gather+self) + b1)
    gemm_kernel<IN_DIM><<<1024, 256, 0, stream>>>(x, W1, dis, hd);
    pull_kernel<0><<<PBLK, 256, 0, stream>>>(hd, dis, base, csr, b1,
                                             act, nullptr, nullptr, nullptr);

    // layer 2: hd = bf16((act@W2)*dis) ; fused relu+b2+mean-pool atomics
    gemm_kernel<HIDDEN><<<1024, 256, 0, stream>>>(act, W2, dis, hd);
    pull_kernel<1><<<PBLK, 256, 0, stream>>>(hd, dis, base, csr, b2,
                                             nullptr, batch, pool, cnt);

    final_kernel<<<(N_GRAPHS * HIDDEN + 255) / 256, 256, 0, stream>>>(pool, cnt, out);
}

// Round 4
// 839.375 us; speedup vs baseline: 1.3472x; 1.2010x over previous
//
#include <hip/hip_runtime.h>
#include <hip/hip_bf16.h>

#define N_NODES 100000
#define N_EDGES 3200000
#define IN_DIM 128
#define HIDDEN 64
#define N_GRAPHS 512
#define SCAN_BLOCKS 391   // ceil(N_NODES/256)

typedef __hip_bfloat16 bf16;
__device__ __forceinline__ float b2f(bf16 v) { return __bfloat162float(v); }

// ---------------- CSR build ----------------
__global__ void deg_count_kernel(const int* __restrict__ dst, int* __restrict__ deg) {
    int e = blockIdx.x * blockDim.x + threadIdx.x;
    if (e < N_EDGES) atomicAdd(&deg[dst[e]], 1);
}

__global__ __launch_bounds__(256) void scan1_kernel(const int* __restrict__ cnt,
                                                    int* __restrict__ partials) {
    __shared__ int sd[256];
    int t = threadIdx.x;
    int i = blockIdx.x * 256 + t;
    sd[t] = (i < N_NODES) ? cnt[i] : 0;
    __syncthreads();
    for (int s = 128; s > 0; s >>= 1) {
        if (t < s) sd[t] += sd[t + s];
        __syncthreads();
    }
    if (t == 0) partials[blockIdx.x] = sd[0];
}

__global__ __launch_bounds__(512) void scan2_kernel(int* __restrict__ partials) {
    __shared__ int sd[512];
    int t = threadIdx.x;
    int v = (t < SCAN_BLOCKS) ? partials[t] : 0;
    sd[t] = v;
    __syncthreads();
    for (int off = 1; off < 512; off <<= 1) {
        int u = (t >= off) ? sd[t - off] : 0;
        __syncthreads();
        sd[t] += u;
        __syncthreads();
    }
    partials[t] = sd[t] - v;   // exclusive prefix
}

__global__ __launch_bounds__(256) void scan3_kernel(const int* __restrict__ cnt,
                                                    const int* __restrict__ partials,
                                                    int* __restrict__ base,
                                                    float* __restrict__ dis) {
    __shared__ int sd[256];
    int t = threadIdx.x;
    int i = blockIdx.x * 256 + t;
    int v = (i < N_NODES) ? cnt[i] : 0;
    sd[t] = v;
    __syncthreads();
    for (int off = 1; off < 256; off <<= 1) {
        int u = (t >= off) ? sd[t - off] : 0;
        __syncthreads();
        sd[t] += u;
        __syncthreads();
    }
    if (i < N_NODES) {
        base[i] = partials[blockIdx.x] + sd[t] - v;     // exclusive
        dis[i] = rsqrtf((float)(v + 1));                // +1 self-loop
    }
    if (blockIdx.x == 0 && t == 0) base[N_NODES] = N_EDGES;
}

__global__ void fill_kernel(const int* __restrict__ src, const int* __restrict__ dst,
                            const int* __restrict__ base, int* __restrict__ fcnt,
                            int* __restrict__ csr) {
    int e = blockIdx.x * blockDim.x + threadIdx.x;
    if (e < N_EDGES) {
        int d = dst[e];
        int pos = base[d] + atomicAdd(&fcnt[d], 1);
        csr[pos] = src[e];
    }
}

// ---------------- GEMM: hd[node] = bf16((in[node] @ W) * dis[node]) ----------
// Lane-resident W column + wave-uniform x-row via scalar cache; pure v_fmac.
template <int K>
__global__ __launch_bounds__(256) void gemm_kernel(
        const float* __restrict__ in, const float* __restrict__ W,
        const float* __restrict__ dis, bf16* __restrict__ hd) {
    int tid = threadIdx.x;
    int lane = tid & 63;
    float Wr[K];
    #pragma unroll
    for (int k = 0; k < K; ++k) Wr[k] = W[k * HIDDEN + lane];   // coalesced
    int w = __builtin_amdgcn_readfirstlane(tid >> 6);           // provably uniform
    int wave = blockIdx.x * 4 + w;
    int nw = gridDim.x * 4;
    for (int n0 = wave * 4; n0 < N_NODES; n0 += nw * 4) {
        const float* xr = in + (size_t)n0 * K;
        float a0 = 0.f, a1 = 0.f, a2 = 0.f, a3 = 0.f;
        #pragma unroll
        for (int k = 0; k < K; ++k) {
            float wv = Wr[k];
            a0 = fmaf(xr[k],         wv, a0);
            a1 = fmaf(xr[K + k],     wv, a1);
            a2 = fmaf(xr[2 * K + k], wv, a2);
            a3 = fmaf(xr[3 * K + k], wv, a3);
        }
        bf16* o = hd + (size_t)n0 * HIDDEN + lane;
        o[0]          = __float2bfloat16(a0 * dis[n0]);
        o[HIDDEN]     = __float2bfloat16(a1 * dis[n0 + 1]);
        o[2 * HIDDEN] = __float2bfloat16(a2 * dis[n0 + 2]);
        o[3 * HIDDEN] = __float2bfloat16(a3 * dis[n0 + 3]);
    }
}

// ---------------- pull: row = dis[d]*(sum_src hd[src] + hd[d]) + bias --------
// Round-0 structure (best measured) + persistent waves + 128B-aligned hd rows
// (one cache line per gather, was 2 due to ws offset % 128 == 32) + NT csr.
// POOL=0: act[d] = relu(row) (f32). POOL=1: atomic mean-pool of relu(row).
template <int POOL>
__global__ __launch_bounds__(256) void pull_kernel(
        const bf16* __restrict__ hd, const float* __restrict__ dis,
        const int* __restrict__ base, const int* __restrict__ csr,
        const float* __restrict__ bias,
        float* __restrict__ act,
        const int* __restrict__ batch, float* __restrict__ pool,
        float* __restrict__ cnt) {
    int w = threadIdx.x >> 6, lane = threadIdx.x & 63;
    int wid = blockIdx.x * 4 + w;
    int nwaves = gridDim.x * 4;
    for (int node = wid; node < N_NODES; node += nwaves) {
        int beg = base[node], end = base[node + 1];
        float a0 = 0.f, a1 = 0.f, a2 = 0.f, a3 = 0.f;
        for (int j = beg; j < end; j += 64) {
            int rem = end - j;
            int m = rem < 64 ? rem : 64;
            int idx = (lane < m) ? __builtin_nontemporal_load(&csr[j + lane]) : 0;
            int t = 0;
            for (; t + 8 <= m; t += 8) {
                int s0 = __shfl(idx, t);
                int s1 = __shfl(idx, t + 1);
                int s2 = __shfl(idx, t + 2);
                int s3 = __shfl(idx, t + 3);
                int s4 = __shfl(idx, t + 4);
                int s5 = __shfl(idx, t + 5);
                int s6 = __shfl(idx, t + 6);
                int s7 = __shfl(idx, t + 7);
                float v0 = b2f(hd[(size_t)s0 * HIDDEN + lane]);
                float v1 = b2f(hd[(size_t)s1 * HIDDEN + lane]);
                float v2 = b2f(hd[(size_t)s2 * HIDDEN + lane]);
                float v3 = b2f(hd[(size_t)s3 * HIDDEN + lane]);
                float v4 = b2f(hd[(size_t)s4 * HIDDEN + lane]);
                float v5 = b2f(hd[(size_t)s5 * HIDDEN + lane]);
                float v6 = b2f(hd[(size_t)s6 * HIDDEN + lane]);
                float v7 = b2f(hd[(size_t)s7 * HIDDEN + lane]);
                a0 += v0 + v4;
                a1 += v1 + v5;
                a2 += v2 + v6;
                a3 += v3 + v7;
            }
            for (; t < m; ++t) {
                int s = __shfl(idx, t);
                a0 += b2f(hd[(size_t)s * HIDDEN + lane]);
            }
        }
        float acc = (a0 + a1) + (a2 + a3);
        float self = b2f(hd[(size_t)node * HIDDEN + lane]);
        float row = dis[node] * (acc + self) + bias[lane];
        float v = row > 0.f ? row : 0.f;
        if (POOL == 0) {
            act[(size_t)node * HIDDEN + lane] = v;
        } else {
            int g = batch[node];
            atomicAdd(&pool[g * HIDDEN + lane], v);
            if (lane == 0) atomicAdd(&cnt[g], 1.0f);
        }
    }
}

__global__ void final_kernel(const float* __restrict__ pool,
                             const float* __restrict__ cnt,
                             float* __restrict__ out) {
    int i = blockIdx.x * blockDim.x + threadIdx.x;
    if (i < N_GRAPHS * HIDDEN) {
        float c = cnt[i >> 6];
        c = c > 1.0f ? c : 1.0f;
        out[i] = pool[i] / c;
    }
}

extern "C" void kernel_launch(void* const* d_in, const int* in_sizes, int n_in,
                              void* d_out, int out_size, void* d_ws, size_t ws_size,
                              hipStream_t stream) {
    const float* x  = (const float*)d_in[0];
    const float* W1 = (const float*)d_in[1];
    const float* b1 = (const float*)d_in[2];
    const float* W2 = (const float*)d_in[3];
    const float* b2 = (const float*)d_in[4];
    const int* edge_index = (const int*)d_in[5];
    const int* batch      = (const int*)d_in[6];
    float* out = (float*)d_out;
    (void)in_sizes; (void)n_in; (void)out_size; (void)ws_size;

    // All offsets 256B-aligned so bf16 hd rows (128 B) occupy exactly ONE
    // cache line (previous layout had everything at offset%128==32 ->
    // every gather straddled two lines).
    char* ws = (char*)d_ws;
    int*   deg_cnt  = (int*)  (ws + 0);          // 400000
    int*   fcnt     = (int*)  (ws + 400384);     // 400000
    float* pool     = (float*)(ws + 800768);     // 131072
    float* cnt      = (float*)(ws + 931840);     // 2048
    int*   partials = (int*)  (ws + 933888);     // 2048
    float* dis      = (float*)(ws + 935936);     // 400000
    int*   base     = (int*)  (ws + 1336320);    // 400004 (+pad)
    int*   csr      = (int*)  (ws + 1736448);    // 12800000
    bf16*  hd       = (bf16*) (ws + 14536448);   // 12800000
    float* act      = (float*)(ws + 27336448);   // 25600000 -> ends 52936448

    const int* srcv = edge_index;            // edge_index[0]
    const int* dstv = edge_index + N_EDGES;  // edge_index[1]

    // zero: deg_cnt, fcnt, pool, cnt (contiguous region incl. pads)
    hipMemsetAsync(ws, 0, 933888, stream);

    // CSR build (reused by both layers)
    deg_count_kernel<<<(N_EDGES + 255) / 256, 256, 0, stream>>>(dstv, deg_cnt);
    scan1_kernel<<<SCAN_BLOCKS, 256, 0, stream>>>(deg_cnt, partials);
    scan2_kernel<<<1, 512, 0, stream>>>(partials);
    scan3_kernel<<<SCAN_BLOCKS, 256, 0, stream>>>(deg_cnt, partials, base, dis);
    fill_kernel<<<(N_EDGES + 255) / 256, 256, 0, stream>>>(srcv, dstv, base, fcnt, csr);

    // layer 1: hd = bf16((x@W1)*dis) ; act = relu(dis*(gather+self) + b1)
    gemm_kernel<IN_DIM><<<1024, 256, 0, stream>>>(x, W1, dis, hd);
    pull_kernel<0><<<2048, 256, 0, stream>>>(hd, dis, base, csr, b1,
                                             act, nullptr, nullptr, nullptr);

    // layer 2: hd = bf16((act@W2)*dis) ; fused relu+b2+mean-pool atomics
    gemm_kernel<HIDDEN><<<1024, 256, 0, stream>>>(act, W2, dis, hd);
    pull_kernel<1><<<2048, 256, 0, stream>>>(hd, dis, base, csr, b2,
                                             nullptr, batch, pool, cnt);

    final_kernel<<<(N_GRAPHS * HIDDEN + 255) / 256, 256, 0, stream>>>(pool, cnt, out);
}